// Round 1
// baseline (4091.109 us; speedup 1.0000x reference)
//
#include <hip/hip_runtime.h>
#include <hip/hip_bf16.h>

#define BTOT 8576      // 64*134
#define SEQ 288
#define NF 16
#define SP 292         // padded LDS row stride (292%32==4 -> <=2-way conflicts, f4-aligned)

__global__ __launch_bounds__(256) void stconv_fused(
    const float* __restrict__ src,
    const int*   __restrict__ eidx,
    const float* __restrict__ Wl,
    const float* __restrict__ Wr,
    const float* __restrict__ bgcn,
    const float* __restrict__ cw1g,
    const float* __restrict__ cw2g,
    const float* __restrict__ fcwg,
    const float* __restrict__ fcbg,
    float*       __restrict__ out)
{
    __shared__ float xs[NF][SP];    // x2[f][s]
    __shared__ float ms[NF][SP];    // mean[f][s]
    __shared__ float fs[NF][SP];    // feat[n][t]
    __shared__ float cs[NF][SP];    // conv[fo][s]
    __shared__ float Msc[16][16];   // row-normalized adjacency
    __shared__ float cw1[16*16*3];
    __shared__ float cw2[16*16*5];
    __shared__ float fcw[512];
    __shared__ float fcb[16];

    const int b   = blockIdx.x;
    const int tid = threadIdx.x;
    const float* srcb = src + (size_t)b * (SEQ * NF);

    // ---- phase 0a: zero adjacency ----
    Msc[tid >> 4][tid & 15] = 0.0f;
    __syncthreads();

    // ---- phase 0b: edges (atomic), weight staging, x load ----
    if (tid < 96) {
        int es = eidx[tid];
        int ed = eidx[96 + tid];
        atomicAdd(&Msc[ed][es], 1.0f);
    }
    for (int i = tid; i < 768;  i += 256) cw1[i] = cw1g[i];
    for (int i = tid; i < 1280; i += 256) cw2[i] = cw2g[i];
    for (int i = tid; i < 512;  i += 256) fcw[i] = fcwg[i];
    if (tid < 16) fcb[tid] = fcbg[tid];

    // load x: src[b][s][f] -> xs[f][s]   (coalesced global read)
    for (int i = 0; i < 18; ++i) {
        int idx = i * 256 + tid;            // 0..4607
        int s = idx >> 4, f = idx & 15;
        xs[f][s] = srcb[idx];
    }
    if (tid < 64) { int f = tid >> 2, e = tid & 3; xs[f][288 + e] = 0.0f; }
    __syncthreads();

    // ---- phase 0c: row-normalize adjacency ----
    if (tid < 16) {
        float deg = 0.0f;
        #pragma unroll
        for (int f = 0; f < 16; ++f) deg += Msc[tid][f];
        float inv = 1.0f / fmaxf(deg, 1.0f);
        #pragma unroll
        for (int f = 0; f < 16; ++f) Msc[tid][f] *= inv;
    }
    __syncthreads();

    // ---- phase 1: mean = M * x ----
    for (int i = 0; i < 18; ++i) {
        int idx = i * 256 + tid;
        int d = idx / 288, s = idx % 288;
        float a = 0.0f;
        #pragma unroll
        for (int f = 0; f < 16; ++f) a += Msc[d][f] * xs[f][s];
        ms[d][s] = a;
    }
    __syncthreads();

    // ---- phase 2a: GCN GEMM  feat[n][t] = sum_s ms[n][s]*Wl[t][s] + xs[n][s]*Wr[t][s] + b[t]
    {
        const int n  = tid & 15;
        const int tc = tid >> 4;         // 0..15
        float acc[18];
        #pragma unroll
        for (int j = 0; j < 18; ++j) acc[j] = 0.0f;

        for (int s0 = 0; s0 < 288; s0 += 4) {
            float4 xv = *(const float4*)&xs[n][s0];
            float4 mv = *(const float4*)&ms[n][s0];
            #pragma unroll
            for (int j = 0; j < 18; ++j) {
                const int t = tc + (j << 4);
                const float4 wl = *(const float4*)(Wl + t * 288 + s0);
                const float4 wr = *(const float4*)(Wr + t * 288 + s0);
                acc[j] += mv.x * wl.x + mv.y * wl.y + mv.z * wl.z + mv.w * wl.w
                        + xv.x * wr.x + xv.y * wr.y + xv.z * wr.z + xv.w * wr.w;
            }
        }
        #pragma unroll
        for (int j = 0; j < 18; ++j) {
            const int t = tc + (j << 4);
            fs[n][t] = acc[j] + bgcn[t];
        }
    }

    // ---- phase 2b: temporal convs (k=3 pad1 + k=5 pad2), fused taps ----
    {
        const int fo = tid >> 4;         // 0..15
        const int sc = tid & 15;         // 0..15
        const int sbase = sc * 18;
        float acc[18];
        #pragma unroll
        for (int j = 0; j < 18; ++j) acc[j] = 0.0f;

        for (int fi = 0; fi < 16; ++fi) {
            float win[22];
            #pragma unroll
            for (int w = 0; w < 22; ++w) {
                int s = sbase - 2 + w;                 // up to sbase+19 <= 289 (zero-padded)
                win[w] = (s >= 0) ? xs[fi][s] : 0.0f;
            }
            const float* w1 = &cw1[(fo * 16 + fi) * 3];
            const float* w2 = &cw2[(fo * 16 + fi) * 5];
            const float t0 = w2[0];
            const float t1 = w1[0] + w2[1];
            const float t2 = w1[1] + w2[2];
            const float t3 = w1[2] + w2[3];
            const float t4 = w2[4];
            #pragma unroll
            for (int j = 0; j < 18; ++j) {
                acc[j] += t0 * win[j] + t1 * win[j + 1] + t2 * win[j + 2]
                        + t3 * win[j + 3] + t4 * win[j + 4];
            }
        }
        #pragma unroll
        for (int j = 0; j < 18; ++j) cs[fo][sbase + j] = acc[j];
    }
    __syncthreads();

    // ---- phase 3: fc + residual + store ----
    float* outb = out + (size_t)b * (SEQ * NF);
    for (int i = 0; i < 18; ++i) {
        int idx = i * 256 + tid;
        int s = idx >> 4, o = idx & 15;
        float a = fcb[o];
        #pragma unroll
        for (int f = 0; f < 16; ++f) a += fcw[o * 32 + f]      * fs[f][s];
        #pragma unroll
        for (int f = 0; f < 16; ++f) a += fcw[o * 32 + 16 + f] * cs[f][s];
        outb[idx] = xs[o][s] + a;   // xs[o][s] == src[b][s][o]
    }
}

extern "C" void kernel_launch(void* const* d_in, const int* in_sizes, int n_in,
                              void* d_out, int out_size, void* d_ws, size_t ws_size,
                              hipStream_t stream)
{
    const float* src  = (const float*)d_in[0];
    const int*   eidx = (const int*)  d_in[1];
    const float* Wl   = (const float*)d_in[2];
    const float* Wr   = (const float*)d_in[3];
    const float* bgcn = (const float*)d_in[4];
    const float* cw1  = (const float*)d_in[5];
    const float* cw2  = (const float*)d_in[6];
    const float* fcw  = (const float*)d_in[7];
    const float* fcb  = (const float*)d_in[8];
    float* out = (float*)d_out;

    stconv_fused<<<dim3(BTOT), dim3(256), 0, stream>>>(
        src, eidx, Wl, Wr, bgcn, cw1, cw2, fcw, fcb, out);
}

// Round 2
// 519.924 us; speedup vs baseline: 7.8687x; 7.8687x over previous
//
#include <hip/hip_runtime.h>
#include <hip/hip_bf16.h>

typedef short short8 __attribute__((ext_vector_type(8)));
typedef float float4v __attribute__((ext_vector_type(4)));
typedef unsigned short ushort4v __attribute__((ext_vector_type(4)));

#define BTOT 8576
#define SEQ 288
#define NF 16
#define SPN 296      // xsN/msN row stride (ushort): 592B -> ~2-way banks
#define XTROWS 294   // xsT rows: s=-2..291 (idx = s+2)
#define CATW 40      // cat row stride: 80B -> 2-way banks, 16B-aligned
#define WCVW 104     // wcv row stride: 208B -> 2-way banks

__device__ __forceinline__ unsigned short f2b(float f) {
    union { float f; unsigned u; } v; v.f = f;
    unsigned r = v.u + 0x7FFF + ((v.u >> 16) & 1);   // RNE
    return (unsigned short)(r >> 16);
}

// one-time Wl/Wr fp32 -> bf16 into workspace (331,776 B)
__global__ void wcast_kernel(const float* __restrict__ a, const float* __restrict__ b,
                             unsigned short* __restrict__ o) {
    int i = blockIdx.x * 256 + threadIdx.x;     // grid 324*256 = 82944 exact
    o[i]         = f2b(a[i]);
    o[82944 + i] = f2b(b[i]);
}

template<int WPRE>
__global__ __launch_bounds__(256, 2) void stconv_mfma(
    const float* __restrict__ src,
    const int*   __restrict__ eidx,
    const float* __restrict__ Wlf,
    const float* __restrict__ Wrf,
    const unsigned short* __restrict__ Wbf,   // bf16 [Wl|Wr], used when WPRE=1
    const float* __restrict__ bgcn,
    const float* __restrict__ cw1g,
    const float* __restrict__ cw2g,
    const float* __restrict__ fcwg,
    const float* __restrict__ fcbg,
    float*       __restrict__ out)
{
    __shared__ unsigned short xsT[XTROWS * 16];  // x[s][f] (s shifted +2), bf16
    __shared__ unsigned short xsN[16 * SPN];     // x[f][s], bf16  (GCN B-operand)
    __shared__ unsigned short msN[16 * SPN];     // mean[f][s], bf16
    __shared__ unsigned short cat[SEQ * CATW];   // [pos][0:16]=feat^T, [16:32]=conv^T
    __shared__ unsigned short wcv[16 * WCVW];    // conv taps [fo][k=d*16+fi], k<80, rest 0
    __shared__ unsigned short fcwB[16 * 40];     // fc_w [o][f]
    __shared__ unsigned short MB[16 * 40];       // adjacency [d][f], f>=16 zero
    __shared__ float bg[SEQ];
    __shared__ float Msc[256];
    __shared__ float fcb[16];

    const int tid  = threadIdx.x;
    const int wav  = tid >> 6;
    const int lane = tid & 63;
    const int li   = lane & 15;
    const int g    = lane >> 4;
    const int b    = blockIdx.x;
    const float* srcb = src + (size_t)b * (SEQ * NF);

    // ---- P1: zero-init ----
    Msc[tid] = 0.0f;
    for (int i = tid; i < 16 * 40; i += 256) MB[i] = 0;
    for (int i = tid; i < 16 * WCVW; i += 256) wcv[i] = 0;
    if (tid < 96) {  // xsT pad rows idx {0,1,290,291,292,293}
        int r = tid >> 4, f = tid & 15;
        int row = (r < 2) ? r : 288 + r;
        xsT[row * 16 + f] = 0;
    }
    __syncthreads();

    // ---- P2: edges, x staging (2 layouts), weight staging ----
    if (tid < 96) atomicAdd(&Msc[eidx[96 + tid] * 16 + eidx[tid]], 1.0f);
    #pragma unroll
    for (int i = 0; i < 18; ++i) {
        int idx = i * 256 + tid, s = idx >> 4, f = idx & 15;
        unsigned short h = f2b(srcb[idx]);
        xsT[(s + 2) * 16 + f] = h;
        xsN[f * SPN + s]      = h;
    }
    for (int j = tid; j < 1280; j += 256) {      // fused conv taps: T[d]=w2[d]+w1[d-1]
        int fo = j / 80, rem = j % 80, fi = rem / 5, d = rem % 5;
        float t = cw2g[(fo * 16 + fi) * 5 + d];
        if (d >= 1 && d <= 3) t += cw1g[(fo * 16 + fi) * 3 + (d - 1)];
        wcv[fo * WCVW + d * 16 + fi] = f2b(t);
    }
    for (int j = tid; j < 512; j += 256) fcwB[(j >> 5) * 40 + (j & 31)] = f2b(fcwg[j]);
    for (int i = tid; i < SEQ; i += 256) bg[i] = bgcn[i];
    if (tid < 16) fcb[tid] = fcbg[tid];
    __syncthreads();

    // ---- P3: row-normalize adjacency -> MB bf16 ----
    if (tid < 16) {
        float deg = 0.0f;
        #pragma unroll
        for (int f = 0; f < 16; ++f) deg += Msc[tid * 16 + f];
        float inv = 1.0f / fmaxf(deg, 1.0f);
        #pragma unroll
        for (int f = 0; f < 16; ++f) MB[tid * 40 + f] = f2b(Msc[tid * 16 + f] * inv);
    }
    __syncthreads();

    // ---- P4: mean = M * x via MFMA.  D[i=s_loc][j=d] ----
    {
        short8 bm = *(const short8*)&MB[li * 40 + 8 * g];
        for (int st = wav; st < 18; st += 4) {
            int s0 = st * 16;
            short8 a = {0, 0, 0, 0, 0, 0, 0, 0};
            if (g < 2) a = *(const short8*)&xsT[(s0 + li + 2) * 16 + 8 * g];
            float4v c = {0.f, 0.f, 0.f, 0.f};
            c = __builtin_amdgcn_mfma_f32_16x16x32_bf16(a, bm, c, 0, 0, 0);
            ushort4v p;
            #pragma unroll
            for (int r = 0; r < 4; ++r) p[r] = f2b(c[r]);
            *(ushort4v*)&msN[li * SPN + s0 + 4 * g] = p;   // mean[d=li][s0+4g..+3]
        }
    }
    __syncthreads();

    // ---- P5: GCN GEMM.  D[i=t_loc][j=n], A=W rows (global), B=ms/xs (LDS) ----
    {
        float4v acc[5];
        #pragma unroll
        for (int m = 0; m < 5; ++m) {
            int tt = wav + 4 * m;
            if (tt < 18) {
                #pragma unroll
                for (int r = 0; r < 4; ++r) acc[m][r] = bg[tt * 16 + 4 * g + r];
            }
        }
        const unsigned short* WblT = Wbf;
        const unsigned short* WbrT = Wbf + 288 * 288;
        #pragma unroll 1
        for (int kk = 0; kk < 18; ++kk) {
            const int s0 = (kk < 9 ? kk : kk - 9) * 32;
            const unsigned short* xsrc = (kk < 9) ? msN : xsN;
            short8 bfr = *(const short8*)&xsrc[li * SPN + s0 + 8 * g];
            #pragma unroll
            for (int m = 0; m < 5; ++m) {
                int tt = wav + 4 * m;
                if (tt < 18) {
                    const int t = tt * 16 + li;
                    short8 a;
                    if (WPRE) {
                        const unsigned short* Wp = (kk < 9) ? WblT : WbrT;
                        a = *(const short8*)&Wp[t * 288 + s0 + 8 * g];
                    } else {
                        const float* Wp = (kk < 9) ? Wlf : Wrf;
                        const float* p = &Wp[t * 288 + s0 + 8 * g];
                        float4 w0 = *(const float4*)p, w1 = *(const float4*)(p + 4);
                        a[0] = (short)f2b(w0.x); a[1] = (short)f2b(w0.y);
                        a[2] = (short)f2b(w0.z); a[3] = (short)f2b(w0.w);
                        a[4] = (short)f2b(w1.x); a[5] = (short)f2b(w1.y);
                        a[6] = (short)f2b(w1.z); a[7] = (short)f2b(w1.w);
                    }
                    acc[m] = __builtin_amdgcn_mfma_f32_16x16x32_bf16(a, bfr, acc[m], 0, 0, 0);
                }
            }
        }
        #pragma unroll
        for (int m = 0; m < 5; ++m) {
            int tt = wav + 4 * m;
            if (tt < 18) {
                #pragma unroll
                for (int r = 0; r < 4; ++r)
                    cat[(tt * 16 + 4 * g + r) * CATW + li] = f2b(acc[m][r]);
            }
        }
    }

    // ---- P6: conv via MFMA.  D[i=s_loc][j=fo], K=96 (=6 shifts d, d=5 zero-wt) ----
    {
        short8 cb0 = *(const short8*)&wcv[li * WCVW + 0  + 8 * g];
        short8 cb1 = *(const short8*)&wcv[li * WCVW + 32 + 8 * g];
        short8 cb2 = *(const short8*)&wcv[li * WCVW + 64 + 8 * g];
        const int fi0   = (g & 1) * 8;
        const int dbase = g >> 1;
        for (int st = wav; st < 18; st += 4) {
            int s0 = st * 16;
            int rbase = (s0 + li + dbase) * 16 + fi0;   // xsT idx = s0+li+d (shift +2 folded)
            short8 a0 = *(const short8*)&xsT[rbase];
            short8 a1 = *(const short8*)&xsT[rbase + 32];
            short8 a2 = *(const short8*)&xsT[rbase + 64];
            float4v c = {0.f, 0.f, 0.f, 0.f};
            c = __builtin_amdgcn_mfma_f32_16x16x32_bf16(a0, cb0, c, 0, 0, 0);
            c = __builtin_amdgcn_mfma_f32_16x16x32_bf16(a1, cb1, c, 0, 0, 0);
            c = __builtin_amdgcn_mfma_f32_16x16x32_bf16(a2, cb2, c, 0, 0, 0);
            #pragma unroll
            for (int r = 0; r < 4; ++r)
                cat[(s0 + 4 * g + r) * CATW + 16 + li] = f2b(c[r]);
        }
    }
    __syncthreads();

    // ---- P7: fc + bias + residual via MFMA.  D[i=pos_loc][j=o], C=src+fc_b ----
    {
        short8 fb = *(const short8*)&fcwB[li * 40 + 8 * g];
        float* outb = out + (size_t)b * (SEQ * NF);
        for (int st = wav; st < 18; st += 4) {
            int s0 = st * 16;
            float4v c;
            #pragma unroll
            for (int r = 0; r < 4; ++r) c[r] = srcb[(s0 + 4 * g + r) * 16 + li] + fcb[li];
            short8 a = *(const short8*)&cat[(s0 + li) * CATW + 8 * g];
            c = __builtin_amdgcn_mfma_f32_16x16x32_bf16(a, fb, c, 0, 0, 0);
            #pragma unroll
            for (int r = 0; r < 4; ++r) outb[(s0 + 4 * g + r) * 16 + li] = c[r];
        }
    }
}

extern "C" void kernel_launch(void* const* d_in, const int* in_sizes, int n_in,
                              void* d_out, int out_size, void* d_ws, size_t ws_size,
                              hipStream_t stream)
{
    const float* src  = (const float*)d_in[0];
    const int*   eidx = (const int*)  d_in[1];
    const float* Wl   = (const float*)d_in[2];
    const float* Wr   = (const float*)d_in[3];
    const float* bgcn = (const float*)d_in[4];
    const float* cw1  = (const float*)d_in[5];
    const float* cw2  = (const float*)d_in[6];
    const float* fcw  = (const float*)d_in[7];
    const float* fcb  = (const float*)d_in[8];
    float* out = (float*)d_out;

    const size_t wbytes = (size_t)2 * 288 * 288 * sizeof(unsigned short);
    if (ws_size >= wbytes) {
        wcast_kernel<<<dim3(324), dim3(256), 0, stream>>>(Wl, Wr, (unsigned short*)d_ws);
        stconv_mfma<1><<<dim3(BTOT), dim3(256), 0, stream>>>(
            src, eidx, Wl, Wr, (const unsigned short*)d_ws,
            bgcn, cw1, cw2, fcw, fcb, out);
    } else {
        stconv_mfma<0><<<dim3(BTOT), dim3(256), 0, stream>>>(
            src, eidx, Wl, Wr, nullptr,
            bgcn, cw1, cw2, fcw, fcb, out);
    }
}

// Round 3
// 233.979 us; speedup vs baseline: 17.4849x; 2.2221x over previous
//
#include <hip/hip_runtime.h>
#include <hip/hip_bf16.h>

typedef short short8 __attribute__((ext_vector_type(8)));
typedef float float4v __attribute__((ext_vector_type(4)));
typedef unsigned short ushort4v __attribute__((ext_vector_type(4)));

#define BTOT 8576
#define SEQ 288
#define NF 16
#define SPN 296      // xsN/msN row stride (ushort)
#define XTROWS 294   // xsT rows: s=-2..291 (idx = s+2)
#define CATW 40      // cat row stride (ushort)
#define WCVW 104     // wcv row stride (ushort)

#define XT_USH (XTROWS * 16)          // 4704
#define XN_USH (16 * SPN)             // 4736
#define POOL_USH (XT_USH + 2 * XN_USH) // 14176 (cat needs 288*40=11520 <= pool)

__device__ __forceinline__ unsigned short f2b(float f) {
    union { float f; unsigned u; } v; v.f = f;
    unsigned r = v.u + 0x7FFF + ((v.u >> 16) & 1);   // RNE
    return (unsigned short)(r >> 16);
}

// one-time Wl/Wr fp32 -> bf16 into workspace (331,776 B)
__global__ void wcast_kernel(const float* __restrict__ a, const float* __restrict__ b,
                             unsigned short* __restrict__ o) {
    int i = blockIdx.x * 256 + threadIdx.x;     // grid 324*256 = 82944 exact
    o[i]         = f2b(a[i]);
    o[82944 + i] = f2b(b[i]);
}

#define LOADK(KK, A_, B_) do {                                                     \
    const int s0_ = ((KK) < 9 ? (KK) : (KK) - 9) * 32;                             \
    const unsigned short* xsrc_ = ((KK) < 9) ? msN : xsN;                          \
    (B_) = *(const short8*)&xsrc_[li * SPN + s0_ + 8 * g];                         \
    const unsigned short* Wp_ = ((KK) < 9) ? WblT : WbrT;                          \
    _Pragma("unroll")                                                              \
    for (int m_ = 0; m_ < 5; ++m_) {                                               \
        int tt_ = wav + 4 * m_;                                                    \
        if (tt_ < 18)                                                              \
            (A_)[m_] = *(const short8*)&Wp_[(tt_ * 16 + li) * 288 + s0_ + 8 * g];  \
    }                                                                              \
} while (0)

template<int WPRE>
__global__ __launch_bounds__(256, 4) void stconv_mfma(
    const float* __restrict__ src,
    const int*   __restrict__ eidx,
    const float* __restrict__ Wlf,
    const float* __restrict__ Wrf,
    const unsigned short* __restrict__ Wbf,
    const float* __restrict__ bgcn,
    const float* __restrict__ cw1g,
    const float* __restrict__ cw2g,
    const float* __restrict__ fcwg,
    const float* __restrict__ fcbg,
    float*       __restrict__ out)
{
    __shared__ unsigned short pool[POOL_USH];
    __shared__ unsigned short wcv[16 * WCVW];
    __shared__ unsigned short fcwB[16 * 40];
    __shared__ unsigned short MB[16 * 40];
    __shared__ float bg[SEQ];
    __shared__ float Msc[256];
    __shared__ float fcb[16];

    unsigned short* xsT = pool;                    // x[s][f] (s shifted +2)
    unsigned short* xsN = pool + XT_USH;           // x[f][s]
    unsigned short* msN = pool + XT_USH + XN_USH;  // mean[f][s]
    unsigned short* cat = pool;                    // ALIAS: valid after pool reads done

    const int tid  = threadIdx.x;
    const int wav  = tid >> 6;
    const int lane = tid & 63;
    const int li   = lane & 15;
    const int g    = lane >> 4;
    const int b    = blockIdx.x;
    const float* srcb = src + (size_t)b * (SEQ * NF);

    // ---- P1: zero-init ----
    Msc[tid] = 0.0f;
    for (int i = tid; i < 16 * 40; i += 256) MB[i] = 0;
    for (int i = tid; i < 16 * WCVW; i += 256) wcv[i] = 0;
    if (tid < 96) {  // xsT pad rows idx {0,1,290,291,292,293}
        int r = tid >> 4, f = tid & 15;
        int row = (r < 2) ? r : 288 + r;
        xsT[row * 16 + f] = 0;
    }
    __syncthreads();

    // ---- P2: edges, x staging (float4 loads), weight staging ----
    if (tid < 96) atomicAdd(&Msc[eidx[96 + tid] * 16 + eidx[tid]], 1.0f);
    #pragma unroll
    for (int i = 0; i < 5; ++i) {
        int c = i * 256 + tid;                     // float4 index, 1152 total
        if (c < 1152) {
            int s = c >> 2, f0 = (c & 3) << 2;
            float4 v = *(const float4*)(srcb + (c << 2));
            ushort4v h;
            h[0] = f2b(v.x); h[1] = f2b(v.y); h[2] = f2b(v.z); h[3] = f2b(v.w);
            *(ushort4v*)&xsT[(s + 2) * 16 + f0] = h;
            xsN[(f0 + 0) * SPN + s] = h[0];
            xsN[(f0 + 1) * SPN + s] = h[1];
            xsN[(f0 + 2) * SPN + s] = h[2];
            xsN[(f0 + 3) * SPN + s] = h[3];
        }
    }
    for (int j = tid; j < 1280; j += 256) {        // fused conv taps: T[d]=w2[d]+w1[d-1]
        int fo = j / 80, rem = j % 80, fi = rem / 5, d = rem % 5;
        float t = cw2g[(fo * 16 + fi) * 5 + d];
        if (d >= 1 && d <= 3) t += cw1g[(fo * 16 + fi) * 3 + (d - 1)];
        wcv[fo * WCVW + d * 16 + fi] = f2b(t);
    }
    for (int j = tid; j < 512; j += 256) fcwB[(j >> 5) * 40 + (j & 31)] = f2b(fcwg[j]);
    for (int i = tid; i < SEQ; i += 256) bg[i] = bgcn[i];
    if (tid < 16) fcb[tid] = fcbg[tid];
    __syncthreads();

    // ---- P3: row-normalize adjacency -> MB bf16 ----
    if (tid < 16) {
        float deg = 0.0f;
        #pragma unroll
        for (int f = 0; f < 16; ++f) deg += Msc[tid * 16 + f];
        float inv = 1.0f / fmaxf(deg, 1.0f);
        #pragma unroll
        for (int f = 0; f < 16; ++f) MB[tid * 40 + f] = f2b(Msc[tid * 16 + f] * inv);
    }
    __syncthreads();

    // ---- P4: mean = M * x via MFMA ----
    {
        short8 bm = *(const short8*)&MB[li * 40 + 8 * g];
        for (int st = wav; st < 18; st += 4) {
            int s0 = st * 16;
            short8 a = {0, 0, 0, 0, 0, 0, 0, 0};
            if (g < 2) a = *(const short8*)&xsT[(s0 + li + 2) * 16 + 8 * g];
            float4v c = {0.f, 0.f, 0.f, 0.f};
            c = __builtin_amdgcn_mfma_f32_16x16x32_bf16(a, bm, c, 0, 0, 0);
            ushort4v p;
            #pragma unroll
            for (int r = 0; r < 4; ++r) p[r] = f2b(c[r]);
            *(ushort4v*)&msN[li * SPN + s0 + 4 * g] = p;
        }
    }
    __syncthreads();

    ushort4v p5o[5];   // deferred feat^T tile (bf16)
    ushort4v p6o[5];   // deferred conv^T tile (bf16)

    // ---- P5: GCN GEMM with register double-buffer prefetch ----
    {
        float4v acc[5];
        #pragma unroll
        for (int m = 0; m < 5; ++m) {
            int tt = wav + 4 * m;
            if (tt < 18) {
                #pragma unroll
                for (int r = 0; r < 4; ++r) acc[m][r] = bg[tt * 16 + 4 * g + r];
            }
        }
        if (WPRE) {
            const unsigned short* WblT = Wbf;
            const unsigned short* WbrT = Wbf + 288 * 288;
            short8 aC[5], aN[5], bC, bN;
            LOADK(0, aC, bC);
            #pragma unroll 1
            for (int kk = 0; kk < 18; kk += 2) {
                LOADK(kk + 1, aN, bN);
                #pragma unroll
                for (int m = 0; m < 5; ++m) {
                    int tt = wav + 4 * m;
                    if (tt < 18)
                        acc[m] = __builtin_amdgcn_mfma_f32_16x16x32_bf16(aC[m], bC, acc[m], 0, 0, 0);
                }
                if (kk < 16) LOADK(kk + 2, aC, bC);
                #pragma unroll
                for (int m = 0; m < 5; ++m) {
                    int tt = wav + 4 * m;
                    if (tt < 18)
                        acc[m] = __builtin_amdgcn_mfma_f32_16x16x32_bf16(aN[m], bN, acc[m], 0, 0, 0);
                }
            }
        } else {
            #pragma unroll 1
            for (int kk = 0; kk < 18; ++kk) {
                const int s0 = (kk < 9 ? kk : kk - 9) * 32;
                const unsigned short* xsrc = (kk < 9) ? msN : xsN;
                short8 bfr = *(const short8*)&xsrc[li * SPN + s0 + 8 * g];
                #pragma unroll
                for (int m = 0; m < 5; ++m) {
                    int tt = wav + 4 * m;
                    if (tt < 18) {
                        const int t = tt * 16 + li;
                        const float* Wp = (kk < 9) ? Wlf : Wrf;
                        const float* p = &Wp[t * 288 + s0 + 8 * g];
                        float4 w0 = *(const float4*)p, w1 = *(const float4*)(p + 4);
                        short8 a;
                        a[0] = (short)f2b(w0.x); a[1] = (short)f2b(w0.y);
                        a[2] = (short)f2b(w0.z); a[3] = (short)f2b(w0.w);
                        a[4] = (short)f2b(w1.x); a[5] = (short)f2b(w1.y);
                        a[6] = (short)f2b(w1.z); a[7] = (short)f2b(w1.w);
                        acc[m] = __builtin_amdgcn_mfma_f32_16x16x32_bf16(a, bfr, acc[m], 0, 0, 0);
                    }
                }
            }
        }
        #pragma unroll
        for (int m = 0; m < 5; ++m) {
            #pragma unroll
            for (int r = 0; r < 4; ++r) p5o[m][r] = f2b(acc[m][r]);
        }
    }

    // ---- P6: conv via MFMA, output to registers ----
    {
        short8 cb0 = *(const short8*)&wcv[li * WCVW + 0  + 8 * g];
        short8 cb1 = *(const short8*)&wcv[li * WCVW + 32 + 8 * g];
        short8 cb2 = *(const short8*)&wcv[li * WCVW + 64 + 8 * g];
        const int fi0   = (g & 1) * 8;
        const int dbase = g >> 1;
        #pragma unroll
        for (int it = 0; it < 5; ++it) {
            int st = wav + 4 * it;
            if (st < 18) {
                int s0 = st * 16;
                int rbase = (s0 + li + dbase) * 16 + fi0;
                short8 a0 = *(const short8*)&xsT[rbase];
                short8 a1 = *(const short8*)&xsT[rbase + 32];
                short8 a2 = *(const short8*)&xsT[rbase + 64];
                float4v c = {0.f, 0.f, 0.f, 0.f};
                c = __builtin_amdgcn_mfma_f32_16x16x32_bf16(a0, cb0, c, 0, 0, 0);
                c = __builtin_amdgcn_mfma_f32_16x16x32_bf16(a1, cb1, c, 0, 0, 0);
                c = __builtin_amdgcn_mfma_f32_16x16x32_bf16(a2, cb2, c, 0, 0, 0);
                #pragma unroll
                for (int r = 0; r < 4; ++r) p6o[it][r] = f2b(c[r]);
            }
        }
    }
    __syncthreads();   // all pool reads done -> cat may overwrite

    // ---- deferred cat writes ----
    #pragma unroll
    for (int m = 0; m < 5; ++m) {
        int tt = wav + 4 * m;
        if (tt < 18) {
            #pragma unroll
            for (int r = 0; r < 4; ++r)
                cat[(tt * 16 + 4 * g + r) * CATW + li] = p5o[m][r];
        }
    }
    #pragma unroll
    for (int it = 0; it < 5; ++it) {
        int st = wav + 4 * it;
        if (st < 18) {
            int s0 = st * 16;
            #pragma unroll
            for (int r = 0; r < 4; ++r)
                cat[(s0 + 4 * g + r) * CATW + 16 + li] = p6o[it][r];
        }
    }
    __syncthreads();

    // ---- P7: fc + bias + residual via MFMA ----
    {
        short8 fb = *(const short8*)&fcwB[li * 40 + 8 * g];
        float* outb = out + (size_t)b * (SEQ * NF);
        for (int st = wav; st < 18; st += 4) {
            int s0 = st * 16;
            float4v c;
            #pragma unroll
            for (int r = 0; r < 4; ++r) c[r] = srcb[(s0 + 4 * g + r) * 16 + li] + fcb[li];
            short8 a = *(const short8*)&cat[(s0 + li) * CATW + 8 * g];
            c = __builtin_amdgcn_mfma_f32_16x16x32_bf16(a, fb, c, 0, 0, 0);
            #pragma unroll
            for (int r = 0; r < 4; ++r) outb[(s0 + 4 * g + r) * 16 + li] = c[r];
        }
    }
}

extern "C" void kernel_launch(void* const* d_in, const int* in_sizes, int n_in,
                              void* d_out, int out_size, void* d_ws, size_t ws_size,
                              hipStream_t stream)
{
    const float* src  = (const float*)d_in[0];
    const int*   eidx = (const int*)  d_in[1];
    const float* Wl   = (const float*)d_in[2];
    const float* Wr   = (const float*)d_in[3];
    const float* bgcn = (const float*)d_in[4];
    const float* cw1  = (const float*)d_in[5];
    const float* cw2  = (const float*)d_in[6];
    const float* fcw  = (const float*)d_in[7];
    const float* fcb  = (const float*)d_in[8];
    float* out = (float*)d_out;

    const size_t wbytes = (size_t)2 * 288 * 288 * sizeof(unsigned short);
    if (ws_size >= wbytes) {
        wcast_kernel<<<dim3(324), dim3(256), 0, stream>>>(Wl, Wr, (unsigned short*)d_ws);
        stconv_mfma<1><<<dim3(BTOT), dim3(256), 0, stream>>>(
            src, eidx, Wl, Wr, (const unsigned short*)d_ws,
            bgcn, cw1, cw2, fcw, fcb, out);
    } else {
        stconv_mfma<0><<<dim3(BTOT), dim3(256), 0, stream>>>(
            src, eidx, Wl, Wr, nullptr,
            bgcn, cw1, cw2, fcw, fcb, out);
    }
}

// Round 4
// 165.345 us; speedup vs baseline: 24.7429x; 1.4151x over previous
//
#include <hip/hip_runtime.h>
#include <hip/hip_bf16.h>

typedef short short8 __attribute__((ext_vector_type(8)));
typedef float float4v __attribute__((ext_vector_type(4)));
typedef unsigned short ushort4v __attribute__((ext_vector_type(4)));

#define BTOT 8576
#define SEQ 288
#define NF 16
#define SPN 296      // xsN/msN row stride (ushort)
#define XTROWS 294   // xsT rows: s=-2..291 (idx = s+2)
#define CATW 40      // cat row stride (ushort)
#define WCVW 104     // wcv row stride (ushort)

#define XT_USH (XTROWS * 16)            // 4704
#define XN_USH (16 * SPN)               // 4736
#define PB (XT_USH + 2 * XN_USH)        // 14176 per-batch pool (cat 288*40=11520 fits)

__device__ __forceinline__ unsigned short f2b(float f) {
    union { float f; unsigned u; } v; v.f = f;
    unsigned r = v.u + 0x7FFF + ((v.u >> 16) & 1);   // RNE
    return (unsigned short)(r >> 16);
}

// one-time Wl/Wr fp32 -> bf16 into workspace (331,776 B)
__global__ void wcast_kernel(const float* __restrict__ a, const float* __restrict__ b,
                             unsigned short* __restrict__ o) {
    int i = blockIdx.x * 256 + threadIdx.x;     // grid 324*256 = 82944 exact
    o[i]         = f2b(a[i]);
    o[82944 + i] = f2b(b[i]);
}

// load K-step KK: A-fragments for this wave's t-tiles (shared by both batches),
// B-fragments for both batches
#define LOADK(KK, A_, B_) do {                                                      \
    const int s0_ = ((KK) < 9 ? (KK) : (KK) - 9) * 32;                              \
    const int moff_ = ((KK) < 9) ? (XT_USH + XN_USH) : XT_USH;                      \
    (B_)[0] = *(const short8*)&pool[moff_ + li * SPN + s0_ + 8 * g];                \
    (B_)[1] = *(const short8*)&pool[PB + moff_ + li * SPN + s0_ + 8 * g];           \
    if (WPRE) {                                                                     \
        const unsigned short* Wp_ = ((KK) < 9) ? WblT : WbrT;                       \
        _Pragma("unroll")                                                           \
        for (int m_ = 0; m_ < 3; ++m_)                                              \
            if (m_ < nt)                                                            \
                (A_)[m_] = *(const short8*)&Wp_[(tts[m_] * 16 + li) * 288 + s0_ + 8 * g]; \
    } else {                                                                        \
        const float* Wp_ = ((KK) < 9) ? Wlf : Wrf;                                  \
        _Pragma("unroll")                                                           \
        for (int m_ = 0; m_ < 3; ++m_)                                              \
            if (m_ < nt) {                                                          \
                const float* p_ = &Wp_[(tts[m_] * 16 + li) * 288 + s0_ + 8 * g];    \
                float4 w0_ = *(const float4*)p_, w1_ = *(const float4*)(p_ + 4);    \
                short8 a_;                                                          \
                a_[0] = (short)f2b(w0_.x); a_[1] = (short)f2b(w0_.y);               \
                a_[2] = (short)f2b(w0_.z); a_[3] = (short)f2b(w0_.w);               \
                a_[4] = (short)f2b(w1_.x); a_[5] = (short)f2b(w1_.y);               \
                a_[6] = (short)f2b(w1_.z); a_[7] = (short)f2b(w1_.w);               \
                (A_)[m_] = a_;                                                      \
            }                                                                       \
    }                                                                               \
} while (0)

#define MFMAK(A_, B_) do {                                                          \
    _Pragma("unroll")                                                               \
    for (int m_ = 0; m_ < 3; ++m_)                                                  \
        if (m_ < nt) {                                                              \
            acc[m_][0] = __builtin_amdgcn_mfma_f32_16x16x32_bf16((A_)[m_], (B_)[0], acc[m_][0], 0, 0, 0); \
            acc[m_][1] = __builtin_amdgcn_mfma_f32_16x16x32_bf16((A_)[m_], (B_)[1], acc[m_][1], 0, 0, 0); \
        }                                                                           \
} while (0)

template<int WPRE>
__global__ __launch_bounds__(512, 4) void stconv_mfma(
    const float* __restrict__ src,
    const int*   __restrict__ eidx,
    const float* __restrict__ Wlf,
    const float* __restrict__ Wrf,
    const unsigned short* __restrict__ Wbf,
    const float* __restrict__ bgcn,
    const float* __restrict__ cw1g,
    const float* __restrict__ cw2g,
    const float* __restrict__ fcwg,
    const float* __restrict__ fcbg,
    float*       __restrict__ out)
{
    __shared__ unsigned short pool[2 * PB];   // 2 batches x {xsT, xsN, msN}; cat aliases
    __shared__ unsigned short wcv[16 * WCVW];
    __shared__ unsigned short fcwB[16 * 40];
    __shared__ unsigned short MB[16 * 40];
    __shared__ float bg[SEQ];
    __shared__ float Msc[256];
    __shared__ float fcb[16];

    const int tid  = threadIdx.x;
    const int wav  = tid >> 6;            // 0..7
    const int nb   = wav >> 2;            // batch of this wave (per-batch phases)
    const int wloc = wav & 3;             // wave index within batch-quad
    const int lane = tid & 63;
    const int li   = lane & 15;
    const int g    = lane >> 4;
    const int b0   = blockIdx.x * 2;

    unsigned short* xsT = pool + nb * PB;                      // x[s][f] (s shifted +2)
    unsigned short* xsN = pool + nb * PB + XT_USH;             // x[f][s]
    unsigned short* msN = pool + nb * PB + XT_USH + XN_USH;    // mean[f][s]
    const float* srcb = src + (size_t)(b0 + nb) * (SEQ * NF);

    // ---- P1: zero-init ----
    if (tid < 256) Msc[tid] = 0.0f;
    for (int i = tid; i < 16 * 40; i += 512) MB[i] = 0;
    for (int i = tid; i < 16 * WCVW; i += 512) wcv[i] = 0;
    if (tid < 192) {   // xsT pad rows {0,1,290..293} for both batches
        int nb2 = tid / 96, r2 = tid % 96;
        int r = r2 >> 4, f = r2 & 15;
        int row = (r < 2) ? r : 288 + r;
        pool[nb2 * PB + row * 16 + f] = 0;
    }
    __syncthreads();

    // ---- P2: edges, x staging (each 4-wave half stages its batch), weights ----
    if (tid < 96) atomicAdd(&Msc[eidx[96 + tid] * 16 + eidx[tid]], 1.0f);
    {
        const int q = tid & 255;
        #pragma unroll
        for (int i = 0; i < 5; ++i) {
            int c = i * 256 + q;                  // float4 index, 1152 per batch
            if (c < 1152) {
                int s = c >> 2, f0 = (c & 3) << 2;
                float4 v = *(const float4*)(srcb + (c << 2));
                ushort4v h;
                h[0] = f2b(v.x); h[1] = f2b(v.y); h[2] = f2b(v.z); h[3] = f2b(v.w);
                *(ushort4v*)&xsT[(s + 2) * 16 + f0] = h;
                xsN[(f0 + 0) * SPN + s] = h[0];
                xsN[(f0 + 1) * SPN + s] = h[1];
                xsN[(f0 + 2) * SPN + s] = h[2];
                xsN[(f0 + 3) * SPN + s] = h[3];
            }
        }
    }
    for (int j = tid; j < 1280; j += 512) {       // fused conv taps: T[d]=w2[d]+w1[d-1]
        int fo = j / 80, rem = j % 80, fi = rem / 5, d = rem % 5;
        float t = cw2g[(fo * 16 + fi) * 5 + d];
        if (d >= 1 && d <= 3) t += cw1g[(fo * 16 + fi) * 3 + (d - 1)];
        wcv[fo * WCVW + d * 16 + fi] = f2b(t);
    }
    if (tid < 512) fcwB[(tid >> 5) * 40 + (tid & 31)] = f2b(fcwg[tid]);
    if (tid < SEQ) bg[tid] = bgcn[tid];
    if (tid < 16) fcb[tid] = fcbg[tid];
    __syncthreads();

    // ---- P3: row-normalize adjacency -> MB bf16 ----
    if (tid < 16) {
        float deg = 0.0f;
        #pragma unroll
        for (int f = 0; f < 16; ++f) deg += Msc[tid * 16 + f];
        float inv = 1.0f / fmaxf(deg, 1.0f);
        #pragma unroll
        for (int f = 0; f < 16; ++f) MB[tid * 40 + f] = f2b(Msc[tid * 16 + f] * inv);
    }
    __syncthreads();

    // ---- P4: mean = M * x via MFMA (each quad on its batch) ----
    {
        short8 bm = *(const short8*)&MB[li * 40 + 8 * g];
        for (int st = wloc; st < 18; st += 4) {
            int s0 = st * 16;
            short8 a = {0, 0, 0, 0, 0, 0, 0, 0};
            if (g < 2) a = *(const short8*)&xsT[(s0 + li + 2) * 16 + 8 * g];
            float4v c = {0.f, 0.f, 0.f, 0.f};
            c = __builtin_amdgcn_mfma_f32_16x16x32_bf16(a, bm, c, 0, 0, 0);
            ushort4v p;
            #pragma unroll
            for (int r = 0; r < 4; ++r) p[r] = f2b(c[r]);
            *(ushort4v*)&msN[li * SPN + s0 + 4 * g] = p;
        }
    }
    __syncthreads();

    // wave -> t-tile assignment: all 18 tiles covered exactly once
    const int t2 = (wav == 0) ? 16 : ((wav == 5) ? 17 : -1);
    const int nt = (t2 >= 0) ? 3 : 2;
    const int tts[3] = {wav, wav + 8, t2};

    ushort4v p5o[3][2];   // deferred feat^T tiles (bf16), [tile][batch]
    ushort4v p6o[5];      // deferred conv^T tile (bf16)

    // ---- P5: GCN GEMM, W fragments shared across both batches ----
    {
        float4v acc[3][2];
        #pragma unroll
        for (int m = 0; m < 3; ++m)
            if (m < nt) {
                #pragma unroll
                for (int r = 0; r < 4; ++r) {
                    float bv = bg[tts[m] * 16 + 4 * g + r];
                    acc[m][0][r] = bv;
                    acc[m][1][r] = bv;
                }
            }
        const unsigned short* WblT = Wbf;
        const unsigned short* WbrT = Wbf + 288 * 288;
        short8 aC[3], aN[3], bC[2], bN[2];
        LOADK(0, aC, bC);
        #pragma unroll 1
        for (int kk = 0; kk < 18; kk += 2) {
            LOADK(kk + 1, aN, bN);
            MFMAK(aC, bC);
            if (kk < 16) LOADK(kk + 2, aC, bC);
            MFMAK(aN, bN);
        }
        #pragma unroll
        for (int m = 0; m < 3; ++m)
            if (m < nt) {
                #pragma unroll
                for (int r = 0; r < 4; ++r) {
                    p5o[m][0][r] = f2b(acc[m][0][r]);
                    p5o[m][1][r] = f2b(acc[m][1][r]);
                }
            }
    }

    // ---- P6: conv via MFMA, output to registers (each quad on its batch) ----
    {
        short8 cb0 = *(const short8*)&wcv[li * WCVW + 0  + 8 * g];
        short8 cb1 = *(const short8*)&wcv[li * WCVW + 32 + 8 * g];
        short8 cb2 = *(const short8*)&wcv[li * WCVW + 64 + 8 * g];
        const int fi0   = (g & 1) * 8;
        const int dbase = g >> 1;
        #pragma unroll
        for (int it = 0; it < 5; ++it) {
            int st = wloc + 4 * it;
            if (st < 18) {
                int s0 = st * 16;
                int rbase = (s0 + li + dbase) * 16 + fi0;
                short8 a0 = *(const short8*)&xsT[rbase];
                short8 a1 = *(const short8*)&xsT[rbase + 32];
                short8 a2 = *(const short8*)&xsT[rbase + 64];
                float4v c = {0.f, 0.f, 0.f, 0.f};
                c = __builtin_amdgcn_mfma_f32_16x16x32_bf16(a0, cb0, c, 0, 0, 0);
                c = __builtin_amdgcn_mfma_f32_16x16x32_bf16(a1, cb1, c, 0, 0, 0);
                c = __builtin_amdgcn_mfma_f32_16x16x32_bf16(a2, cb2, c, 0, 0, 0);
                #pragma unroll
                for (int r = 0; r < 4; ++r) p6o[it][r] = f2b(c[r]);
            }
        }
    }
    __syncthreads();   // all pool reads done -> cat may overwrite

    // ---- deferred cat writes (cat_b aliases batch pool) ----
    #pragma unroll
    for (int m = 0; m < 3; ++m)
        if (m < nt) {
            #pragma unroll
            for (int r = 0; r < 4; ++r) {
                pool[0 * PB + (tts[m] * 16 + 4 * g + r) * CATW + li] = p5o[m][0][r];
                pool[1 * PB + (tts[m] * 16 + 4 * g + r) * CATW + li] = p5o[m][1][r];
            }
        }
    #pragma unroll
    for (int it = 0; it < 5; ++it) {
        int st = wloc + 4 * it;
        if (st < 18) {
            int s0 = st * 16;
            #pragma unroll
            for (int r = 0; r < 4; ++r)
                pool[nb * PB + (s0 + 4 * g + r) * CATW + 16 + li] = p6o[it][r];
        }
    }
    __syncthreads();

    // ---- P7: fc + bias + residual via MFMA (each quad on its batch) ----
    {
        const unsigned short* cat = pool + nb * PB;
        short8 fb = *(const short8*)&fcwB[li * 40 + 8 * g];
        float* outb = out + (size_t)(b0 + nb) * (SEQ * NF);
        for (int st = wloc; st < 18; st += 4) {
            int s0 = st * 16;
            float4v c;
            #pragma unroll
            for (int r = 0; r < 4; ++r) c[r] = srcb[(s0 + 4 * g + r) * 16 + li] + fcb[li];
            short8 a = *(const short8*)&cat[(s0 + li) * CATW + 8 * g];
            c = __builtin_amdgcn_mfma_f32_16x16x32_bf16(a, fb, c, 0, 0, 0);
            #pragma unroll
            for (int r = 0; r < 4; ++r) outb[(s0 + 4 * g + r) * 16 + li] = c[r];
        }
    }
}

extern "C" void kernel_launch(void* const* d_in, const int* in_sizes, int n_in,
                              void* d_out, int out_size, void* d_ws, size_t ws_size,
                              hipStream_t stream)
{
    const float* src  = (const float*)d_in[0];
    const int*   eidx = (const int*)  d_in[1];
    const float* Wl   = (const float*)d_in[2];
    const float* Wr   = (const float*)d_in[3];
    const float* bgcn = (const float*)d_in[4];
    const float* cw1  = (const float*)d_in[5];
    const float* cw2  = (const float*)d_in[6];
    const float* fcw  = (const float*)d_in[7];
    const float* fcb  = (const float*)d_in[8];
    float* out = (float*)d_out;

    const size_t wbytes = (size_t)2 * 288 * 288 * sizeof(unsigned short);
    if (ws_size >= wbytes) {
        wcast_kernel<<<dim3(324), dim3(256), 0, stream>>>(Wl, Wr, (unsigned short*)d_ws);
        stconv_mfma<1><<<dim3(BTOT / 2), dim3(512), 0, stream>>>(
            src, eidx, Wl, Wr, (const unsigned short*)d_ws,
            bgcn, cw1, cw2, fcw, fcb, out);
    } else {
        stconv_mfma<0><<<dim3(BTOT / 2), dim3(512), 0, stream>>>(
            src, eidx, Wl, Wr, nullptr,
            bgcn, cw1, cw2, fcw, fcb, out);
    }
}